// Round 4
// baseline (120.132 us; speedup 1.0000x reference)
//
#include <hip/hip_runtime.h>
#include <hip/hip_bf16.h>

#define N_OBJ   32
#define G_TOTAL 4960      // C(32,3)
#define KTOT    9216      // 9 * 1024; k = p*1024 + x*32 + y,  p = i*3+j
#define N_FILT  16
#define REL_D   16
#define BATCH   32
#define NQ      512
#define ZSPLIT  16
#define KCH     576       // KTOT / ZSPLIT
#define NIT     18        // KCH / 32

typedef __attribute__((ext_vector_type(8))) short bf16x8;
typedef __attribute__((ext_vector_type(4))) float f32x4;

static __device__ inline unsigned short f2bf(float x) {
    union { float f; unsigned int u; } v; v.f = x;
    unsigned int r = v.u + 0x7fffu + ((v.u >> 16) & 1u);   // RNE
    return (unsigned short)(r >> 16);
}
static __device__ inline void gload_lds16(const void* g, void* l) {
    __builtin_amdgcn_global_load_lds(
        (const __attribute__((address_space(1))) unsigned int*)g,
        (__attribute__((address_space(3))) unsigned int*)(unsigned int)(uintptr_t)l,
        16, 0, 0);
}
// unrank lexicographic 3-combination of 32
static __device__ inline void unrank3(int g, int& a, int& b, int& c) {
    int rem = g;
    for (a = 0; a < 30; a++) { int cnt = ((31 - a) * (30 - a)) >> 1; if (rem < cnt) break; rem -= cnt; }
    for (b = a + 1; b < 31; b++) { if (rem < 31 - b) break; rem -= 31 - b; }
    c = b + 1 + rem;
}

// ===== L1: W2 rows (blocks 0..511) + pairconv->Dt (512..1663) =====================
// W2[q][p*1024 + x*32 + y] = sum of nw[q,g] over combos g whose (pos i, pos j) = (x,y)
// Built by scattering only p=1 (0,1), p=2 (0,2), p=5 (1,2); p=3/6/7 are transposes,
// p=0/4/8 are diagonal marginals of p1/p1/p2.
__global__ __launch_bounds__(256) void k_front(const float* __restrict__ logits,
                                               const float* __restrict__ inputs,
                                               const float* __restrict__ filters,
                                               unsigned short* __restrict__ W2,
                                               unsigned short* __restrict__ Dt) {
    __shared__ __align__(16) char smem[37056];
    int t = threadIdx.x;
    int role = blockIdx.x;

    if (role < NQ) {
        float* sp  = (float*)smem;             // 32 floats
        float* red = (float*)(smem + 128);     // 4 floats
        float* W2f = (float*)(smem + 144);     // 9216 f32 = 36864 B
        int q = role;
        if (t < N_OBJ) {
            float x = logits[q * N_OBJ + t];
            sp[t] = (x > 15.f) ? x : log1pf(expf(x));
        }
        for (int i = t; i < KTOT; i += 256) W2f[i] = 0.f;
        __syncthreads();

        int g0 = t * 20;
        int aa, bb, cc;
        unrank3(g0, aa, bb, cc);

        float w[20];
        float lmax = -1e30f;
#pragma unroll
        for (int k = 0; k < 20; k++) {
            float v = -1e30f;
            if (g0 + k < G_TOTAL) v = sp[aa] * sp[bb] * sp[cc];
            w[k] = v;
            lmax = fmaxf(lmax, v);
            cc++;
            if (cc >= 32) { bb++; cc = bb + 1; if (cc >= 32) { aa++; bb = aa + 1; cc = bb + 1; } }
        }
#pragma unroll
        for (int off = 32; off; off >>= 1) lmax = fmaxf(lmax, __shfl_down(lmax, off, 64));
        if ((t & 63) == 0) red[t >> 6] = lmax;
        __syncthreads();
        float wmax = fmaxf(fmaxf(red[0], red[1]), fmaxf(red[2], red[3]));

        float lsum = 0.f;
#pragma unroll
        for (int k = 0; k < 20; k++) {
            float e = (g0 + k < G_TOTAL) ? expf(w[k] - wmax) : 0.f;
            w[k] = e;
            lsum += e;
        }
#pragma unroll
        for (int off = 32; off; off >>= 1) lsum += __shfl_down(lsum, off, 64);
        __syncthreads();
        if ((t & 63) == 0) red[t >> 6] = lsum;
        __syncthreads();
        float inv = 1.f / (red[0] + red[1] + red[2] + red[3]);

        // ---- scatter normalized weights into W01 (run-accumulated), W02, W12 ----
        unrank3(g0, aa, bb, cc);
        float run01 = 0.f;
        int curab = aa * 32 + bb;
#pragma unroll
        for (int k = 0; k < 20; k++) {
            if (g0 + k < G_TOTAL) {
                float nwk = w[k] * inv;
                run01 += nwk;
                atomicAdd(&W2f[2 * 1024 + aa * 32 + cc], nwk);
                atomicAdd(&W2f[5 * 1024 + bb * 32 + cc], nwk);
            }
            cc++;
            if (cc >= 32) {
                if (run01 != 0.f) atomicAdd(&W2f[1 * 1024 + curab], run01);
                run01 = 0.f;
                bb++; cc = bb + 1;
                if (cc >= 32) { aa++; bb = aa + 1; cc = bb + 1; }
                curab = aa * 32 + bb;
            }
        }
        if (run01 != 0.f) atomicAdd(&W2f[1 * 1024 + curab], run01);
        __syncthreads();

        // ---- derived blocks: p3=p1^T, p6=p2^T, p7=p5^T; p0/p4/p8 diag marginals ----
        for (int i = t; i < 1024; i += 256) {
            int x = i >> 5, y = i & 31;
            W2f[3 * 1024 + i] = W2f[1 * 1024 + y * 32 + x];
            W2f[6 * 1024 + i] = W2f[2 * 1024 + y * 32 + x];
            W2f[7 * 1024 + i] = W2f[5 * 1024 + y * 32 + x];
        }
        if (t < 96) {
            int which = t >> 5, idx = t & 31;
            float s = 0.f;
            if (which == 0) {        // p0[a,a] = sum_b W01[a][b]
                for (int u = 0; u < 32; u++) s += W2f[1 * 1024 + idx * 32 + u];
                W2f[idx * 33] = s;
            } else if (which == 1) { // p4[b,b] = sum_a W01[a][b]
                for (int u = 0; u < 32; u++) s += W2f[1 * 1024 + u * 32 + idx];
                W2f[4 * 1024 + idx * 33] = s;
            } else {                 // p8[c,c] = sum_a W02[a][c]
                for (int u = 0; u < 32; u++) s += W2f[2 * 1024 + u * 32 + idx];
                W2f[8 * 1024 + idx * 33] = s;
            }
        }
        __syncthreads();

        // ---- convert + coalesced row write: 9216 bf16 = 4608 uints ----
        unsigned int* dstrow = (unsigned int*)(W2 + (size_t)q * KTOT);
        for (int i = t; i < KTOT / 2; i += 256) {
            unsigned int pk = (unsigned int)f2bf(W2f[2 * i]) |
                              ((unsigned int)f2bf(W2f[2 * i + 1]) << 16);
            dstrow[i] = pk;
        }
    } else {
        // ---------- pairconv: Dt[n=b*16+f][p*1024 + xy] = dot(inputs[b,x,y,:], filters[f,p,:])
        float* flt = (float*)smem;            // [f][p_pad] 16*180 floats
        int bid = role - NQ;                  // 0..1151
        int p = bid >> 7;                     // 0..8
        int xb = bid & 127;
        for (int i = t; i < 576; i += 256) {
            int i4 = i * 4;
            int f = i4 / 144;
            int r = i4 - f * 144;
            *(float4*)&flt[f * 180 + (r >> 4) * 20 + (r & 15)] = *(const float4*)(filters + i4);
        }
        __syncthreads();

        int row = xb * 256 + t;               // b*1024 + xy
        const float4* src = (const float4*)(inputs + (size_t)row * 16);
        float4 s0 = src[0], s1 = src[1], s2 = src[2], s3 = src[3];

        unsigned short outv[16];
        const float* fb = &flt[p * 20];
        int xy = row & 1023, b = row >> 10;
#pragma unroll
        for (int f = 0; f < 16; f++) {
            float4 f0 = *(const float4*)(fb + f * 180);
            float4 f1 = *(const float4*)(fb + f * 180 + 4);
            float4 f2 = *(const float4*)(fb + f * 180 + 8);
            float4 f3 = *(const float4*)(fb + f * 180 + 12);
            float d = s0.x * f0.x + s0.y * f0.y + s0.z * f0.z + s0.w * f0.w;
            d += s1.x * f1.x + s1.y * f1.y + s1.z * f1.z + s1.w * f1.w;
            d += s2.x * f2.x + s2.y * f2.y + s2.z * f2.z + s2.w * f2.w;
            d += s3.x * f3.x + s3.y * f3.y + s3.z * f3.z + s3.w * f3.w;
            outv[f] = f2bf(d);
        }
        // lanes have consecutive xy -> each f-store is wave-contiguous (128 B/wave)
        unsigned short* drow = Dt + (p * 1024 + xy);
#pragma unroll
        for (int f = 0; f < 16; f++)
            drow[(size_t)(b * 16 + f) * KTOT] = outv[f];
    }
}

// ===== L2: part[z] = W2(512xK) x Dt^T tile, split-K, no atomics ===================
__global__ __launch_bounds__(256) void k_gemm(const unsigned short* __restrict__ A,
                                              const unsigned short* __restrict__ Bm,
                                              float* __restrict__ part) {
    __shared__ __align__(16) unsigned short As[2][64 * 32];
    __shared__ __align__(16) unsigned short Bs[2][64 * 32];
    int tid = threadIdx.x;
    int q0 = blockIdx.x * 64, n0 = blockIdx.y * 64, z = blockIdx.z;
    int k0 = z * KCH;
    int wave = tid >> 6, lane = tid & 63;
    int wm = wave & 1, wn = wave >> 1;
    int row16 = lane & 15, quad = lane >> 4;

    int srow = tid >> 2;
    int schunk = (tid & 3) ^ ((srow >> 1) & 3);
    const unsigned short* ga = A + (size_t)(q0 + srow) * KTOT + k0 + schunk * 8;
    const unsigned short* gb = Bm + (size_t)(n0 + srow) * KTOT + k0 + schunk * 8;
    char* lA = (char*)&As[0][0] + tid * 16;
    char* lB = (char*)&Bs[0][0] + tid * 16;

    f32x4 acc[2][2] = {};
    int fchunk = (quad ^ ((row16 >> 1) & 3)) * 8;

    gload_lds16(ga, lA);
    gload_lds16(gb, lB);
    for (int it = 0; it < NIT; ++it) {
        __syncthreads();
        if (it + 1 < NIT) {
            int nb = (it + 1) & 1;
            gload_lds16(ga + (it + 1) * 32, lA + nb * 64 * 32 * 2);
            gload_lds16(gb + (it + 1) * 32, lB + nb * 64 * 32 * 2);
        }
        int buf = it & 1;
        bf16x8 afr[2], bfr[2];
#pragma unroll
        for (int mi = 0; mi < 2; mi++)
            afr[mi] = *(const bf16x8*)&As[buf][(wm * 32 + mi * 16 + row16) * 32 + fchunk];
#pragma unroll
        for (int ni = 0; ni < 2; ni++)
            bfr[ni] = *(const bf16x8*)&Bs[buf][(wn * 32 + ni * 16 + row16) * 32 + fchunk];
#pragma unroll
        for (int mi = 0; mi < 2; mi++)
#pragma unroll
            for (int ni = 0; ni < 2; ni++)
                acc[mi][ni] = __builtin_amdgcn_mfma_f32_16x16x32_bf16(
                    afr[mi], bfr[ni], acc[mi][ni], 0, 0, 0);
    }

    float* pz = part + (size_t)z * (NQ * 512);
#pragma unroll
    for (int mi = 0; mi < 2; mi++)
#pragma unroll
        for (int ni = 0; ni < 2; ni++)
#pragma unroll
            for (int r = 0; r < 4; r++) {
                int q = q0 + wm * 32 + mi * 16 + quad * 4 + r;
                int n = n0 + wn * 32 + ni * 16 + row16;
                pz[q * 512 + n] = acc[mi][ni][r];
            }
}

// ===== L3: reduce 16 split-K partials, remap to out[b][q][r] ======================
__global__ __launch_bounds__(256) void k_reduce(const float* __restrict__ part,
                                                float* __restrict__ out) {
    int gid = blockIdx.x * 256 + threadIdx.x;   // 65536 threads
    int q = gid >> 7;
    int n = (gid & 127) * 4;
    float4 a = *(const float4*)(part + q * 512 + n);
#pragma unroll
    for (int zz = 1; zz < ZSPLIT; zz++) {
        float4 b4 = *(const float4*)(part + (size_t)zz * (NQ * 512) + q * 512 + n);
        a.x += b4.x; a.y += b4.y; a.z += b4.z; a.w += b4.w;
    }
    *(float4*)(out + (size_t)(n >> 4) * (NQ * REL_D) + q * 16 + (n & 15)) = a;
}

extern "C" void kernel_launch(void* const* d_in, const int* in_sizes, int n_in,
                              void* d_out, int out_size, void* d_ws, size_t ws_size,
                              hipStream_t stream) {
    const float* inputs  = (const float*)d_in[0];   // (32,32,32,16)
    const float* logits  = (const float*)d_in[1];   // (512,32)
    const float* filters = (const float*)d_in[2];   // (16,3,3,16)
    float* out = (float*)d_out;                     // (32,512,16)

    char* ws = (char*)d_ws;
    unsigned short* W2 = (unsigned short*)ws;                    //  9,437,184 B
    unsigned short* Dt = (unsigned short*)(ws + 9437184);        //  9,437,184 B
    float*          part = (float*)(ws + 18874368);              // 16,777,216 B

    k_front<<<NQ + 1152, 256, 0, stream>>>(logits, inputs, filters, W2, Dt);
    k_gemm<<<dim3(8, 8, ZSPLIT), 256, 0, stream>>>(W2, Dt, part);
    k_reduce<<<NQ * 512 / 4 / 256, 256, 0, stream>>>(part, out);
}

// Round 7
// 117.176 us; speedup vs baseline: 1.0252x; 1.0252x over previous
//
#include <hip/hip_runtime.h>
#include <hip/hip_bf16.h>

#define N_OBJ   32
#define G_TOTAL 4960      // C(32,3)
#define NPAIR   496       // C(32,2)
#define KTOT    1600      // 3*496 (pairs) + 3*32 (diag) + 16 pad
#define SEG01   0
#define SEG02   496
#define SEG12   992
#define SEGD0   1488
#define SEGD1   1520
#define SEGD2   1552
#define N_FILT  16
#define REL_D   16
#define BATCH   32
#define NQ      512
#define ZSPLIT  5
#define KCH     320       // KTOT / ZSPLIT
#define NIT     10        // KCH / 32

typedef __attribute__((ext_vector_type(8))) short bf16x8;
typedef __attribute__((ext_vector_type(4))) float f32x4;

static __device__ inline unsigned short f2bf(float x) {
    union { float f; unsigned int u; } v; v.f = x;
    unsigned int r = v.u + 0x7fffu + ((v.u >> 16) & 1u);   // RNE
    return (unsigned short)(r >> 16);
}
static __device__ inline void gload_lds16(const void* g, void* l) {
    __builtin_amdgcn_global_load_lds(
        (const __attribute__((address_space(1))) unsigned int*)g,
        (__attribute__((address_space(3))) unsigned int*)(unsigned int)(uintptr_t)l,
        16, 0, 0);
}
// base index of pairs starting with x in lexicographic C(32,2) packing:
// pbase(x) = sum_{u<x} (31-u) = x*(63-x)/2
static __device__ inline int pbase(int x) { return (x * (63 - x)) >> 1; }
// unrank lexicographic 3-combination of 32
static __device__ inline void unrank3(int g, int& a, int& b, int& c) {
    int rem = g;
    for (a = 0; a < 30; a++) { int cnt = ((31 - a) * (30 - a)) >> 1; if (rem < cnt) break; rem -= cnt; }
    for (b = a + 1; b < 31; b++) { if (rem < 31 - b) break; rem -= 31 - b; }
    c = b + 1 + rem;
}
// unrank lexicographic 2-combination of 32
static __device__ inline void unrank2(int u, int& x, int& y) {
    for (x = 0; x < 31; x++) { int len = 31 - x; if (u < len) break; u -= len; }
    y = x + 1 + u;
}
static __device__ inline float dot16(float4 a0, float4 a1, float4 a2, float4 a3,
                                     const float* F) {
    float4 f0 = *(const float4*)(F);
    float4 f1 = *(const float4*)(F + 4);
    float4 f2 = *(const float4*)(F + 8);
    float4 f3 = *(const float4*)(F + 12);
    float d = a0.x * f0.x + a0.y * f0.y + a0.z * f0.z + a0.w * f0.w;
    d += a1.x * f1.x + a1.y * f1.y + a1.z * f1.z + a1.w * f1.w;
    d += a2.x * f2.x + a2.y * f2.y + a2.z * f2.z + a2.w * f2.w;
    d += a3.x * f3.x + a3.y * f3.y + a3.z * f3.z + a3.w * f3.w;
    return d;
}

// ===== L1: packed W' rows (blocks 0..511) + folded pairconv B' (512..543) =========
// out[b,q,f] = sum_{x<y} W01[q,xy]*(Dp1[x,y]+Dp3[y,x]) + W02*(Dp2+Dp6^T)
//            + W12*(Dp5+Dp7^T) + sum_x Wd0*Dp0[x,x] + Wd1*Dp4[x,x] + Wd2*Dp8[x,x]
__global__ __launch_bounds__(256) void k_front(const float* __restrict__ logits,
                                               const float* __restrict__ inputs,
                                               const float* __restrict__ filters,
                                               unsigned short* __restrict__ Wp,
                                               unsigned short* __restrict__ Bp) {
    __shared__ __align__(16) char smem[11648];
    int t = threadIdx.x;
    int role = blockIdx.x;

    if (role < NQ) {
        float* sp  = (float*)smem;             // 32 floats
        float* red = (float*)(smem + 128);     // 4 floats
        float* Wf  = (float*)(smem + 144);     // 1600 f32 = 6400 B
        int q = role;
        if (t < N_OBJ) {
            float x = logits[q * N_OBJ + t];
            sp[t] = (x > 15.f) ? x : log1pf(expf(x));
        }
        for (int i = t; i < KTOT; i += 256) Wf[i] = 0.f;
        __syncthreads();

        int g0 = t * 20;
        int aa, bb, cc;
        unrank3(g0, aa, bb, cc);

        float w[20];
        float lmax = -1e30f;
#pragma unroll
        for (int k = 0; k < 20; k++) {
            float v = -1e30f;
            if (g0 + k < G_TOTAL) v = sp[aa] * sp[bb] * sp[cc];
            w[k] = v;
            lmax = fmaxf(lmax, v);
            cc++;
            if (cc >= 32) { bb++; cc = bb + 1; if (cc >= 32) { aa++; bb = aa + 1; cc = bb + 1; } }
        }
#pragma unroll
        for (int off = 32; off; off >>= 1) lmax = fmaxf(lmax, __shfl_down(lmax, off, 64));
        if ((t & 63) == 0) red[t >> 6] = lmax;
        __syncthreads();
        float wmax = fmaxf(fmaxf(red[0], red[1]), fmaxf(red[2], red[3]));

        float lsum = 0.f;
#pragma unroll
        for (int k = 0; k < 20; k++) {
            float e = (g0 + k < G_TOTAL) ? expf(w[k] - wmax) : 0.f;
            w[k] = e;
            lsum += e;
        }
#pragma unroll
        for (int off = 32; off; off >>= 1) lsum += __shfl_down(lsum, off, 64);
        __syncthreads();
        if ((t & 63) == 0) red[t >> 6] = lsum;
        __syncthreads();
        float inv = 1.f / (red[0] + red[1] + red[2] + red[3]);

        // ---- scatter into packed upper-tri segments (LDS atomics) ----
        if (g0 < G_TOTAL) {
            unrank3(g0, aa, bb, cc);
            int i01 = pbase(aa) + bb - aa - 1;
            int i02 = pbase(aa) + cc - aa - 1;
            int i12 = pbase(bb) + cc - bb - 1;
            float run01 = 0.f;
#pragma unroll
            for (int k = 0; k < 20; k++) {
                if (g0 + k < G_TOTAL) {
                    float nwk = w[k] * inv;
                    run01 += nwk;
                    atomicAdd(&Wf[SEG02 + i02], nwk);
                    atomicAdd(&Wf[SEG12 + i12], nwk);
                }
                cc++; i02++; i12++;
                if (cc >= 32) {
                    if (run01 != 0.f) { atomicAdd(&Wf[SEG01 + i01], run01); run01 = 0.f; }
                    bb++; cc = bb + 1;
                    if (cc >= 32) { aa++; bb = aa + 1; cc = bb + 1; }
                    i01 = pbase(aa) + bb - aa - 1;
                    i02 = pbase(aa) + cc - aa - 1;
                    i12 = pbase(bb) + cc - bb - 1;
                }
            }
            if (run01 != 0.f) atomicAdd(&Wf[SEG01 + i01], run01);
        }
        __syncthreads();

        // ---- diagonal marginals ----
        if (t < 96) {
            int which = t >> 5, idx = t & 31;
            float s = 0.f;
            if (which == 0) {            // Wd0[a] = sum_{b>a} W01[a,b]  (contiguous run)
                int base = pbase(idx);
                for (int u = idx + 1; u < 32; u++) s += Wf[SEG01 + base + u - idx - 1];
                Wf[SEGD0 + idx] = s;
            } else if (which == 1) {     // Wd1[b] = sum_{a<b} W01[a,b]
                for (int a2 = 0; a2 < idx; a2++) s += Wf[SEG01 + pbase(a2) + idx - a2 - 1];
                Wf[SEGD1 + idx] = s;
            } else {                     // Wd2[c] = sum_{b<c} W12[b,c]
                for (int b2 = 0; b2 < idx; b2++) s += Wf[SEG12 + pbase(b2) + idx - b2 - 1];
                Wf[SEGD2 + idx] = s;
            }
        }
        __syncthreads();

        // ---- convert + coalesced row write: 1600 bf16 = 800 uints ----
        unsigned int* dstrow = (unsigned int*)(Wp + (size_t)q * KTOT);
        for (int i = t; i < KTOT / 2; i += 256) {
            unsigned int pk = (unsigned int)f2bf(Wf[2 * i]) |
                              ((unsigned int)f2bf(Wf[2 * i + 1]) << 16);
            dstrow[i] = pk;
        }
    } else {
        // ---------- folded pairconv: one block per batch b ----------
        float* flt = (float*)smem;            // [f][p_pad 20] 16*180 floats = 11520 B
        int b = role - NQ;                    // 0..31
        for (int i = t; i < 576; i += 256) {
            int i4 = i * 4;
            int f = i4 / 144;
            int r = i4 - f * 144;
            *(float4*)&flt[f * 180 + (r >> 4) * 20 + (r & 15)] = *(const float4*)(filters + i4);
        }
        __syncthreads();

        // zero the K-pad columns 1584..1599 for this b's 16 rows
        {
            int f = t >> 4, col = t & 15;
            Bp[((size_t)b * 16 + f) * KTOT + 1584 + col] = 0;
        }

        // 528 work items (496 pairs + 32 diagonals) over 256 threads -> 3 reps
        // [R6 bug: rep<2 covered only u<512, leaving diag x=16..31 unwritten]
#pragma unroll 1
        for (int rep = 0; rep < 3; rep++) {
            int u = t + rep * 256;
            if (u >= 528) break;
            if (u < NPAIR) {
                int x, y; unrank2(u, x, y);
                const float4* rxy = (const float4*)(inputs + (((size_t)b * 32 + x) * 32 + y) * 16);
                const float4* ryx = (const float4*)(inputs + (((size_t)b * 32 + y) * 32 + x) * 16);
                float4 a0 = rxy[0], a1 = rxy[1], a2 = rxy[2], a3 = rxy[3];
                float4 c0 = ryx[0], c1 = ryx[1], c2 = ryx[2], c3 = ryx[3];
#pragma unroll
                for (int f = 0; f < 16; f++) {
                    const float* F = &flt[f * 180];
                    float v01 = dot16(a0, a1, a2, a3, F + 1 * 20) + dot16(c0, c1, c2, c3, F + 3 * 20);
                    float v02 = dot16(a0, a1, a2, a3, F + 2 * 20) + dot16(c0, c1, c2, c3, F + 6 * 20);
                    float v12 = dot16(a0, a1, a2, a3, F + 5 * 20) + dot16(c0, c1, c2, c3, F + 7 * 20);
                    size_t nrow = ((size_t)b * 16 + f) * KTOT;
                    Bp[nrow + SEG01 + u] = f2bf(v01);
                    Bp[nrow + SEG02 + u] = f2bf(v02);
                    Bp[nrow + SEG12 + u] = f2bf(v12);
                }
            } else {
                int x = u - NPAIR;            // diagonal element
                const float4* rxx = (const float4*)(inputs + (((size_t)b * 32 + x) * 32 + x) * 16);
                float4 a0 = rxx[0], a1 = rxx[1], a2 = rxx[2], a3 = rxx[3];
#pragma unroll
                for (int f = 0; f < 16; f++) {
                    const float* F = &flt[f * 180];
                    float v0 = dot16(a0, a1, a2, a3, F + 0 * 20);
                    float v4 = dot16(a0, a1, a2, a3, F + 4 * 20);
                    float v8 = dot16(a0, a1, a2, a3, F + 8 * 20);
                    size_t nrow = ((size_t)b * 16 + f) * KTOT;
                    Bp[nrow + SEGD0 + x] = f2bf(v0);
                    Bp[nrow + SEGD1 + x] = f2bf(v4);
                    Bp[nrow + SEGD2 + x] = f2bf(v8);
                }
            }
        }
    }
}

// ===== L2: part[z] = Wp(512xK) x Bp^T tile, split-K, no atomics ===================
__global__ __launch_bounds__(256) void k_gemm(const unsigned short* __restrict__ A,
                                              const unsigned short* __restrict__ Bm,
                                              float* __restrict__ part) {
    __shared__ __align__(16) unsigned short As[2][64 * 32];
    __shared__ __align__(16) unsigned short Bs[2][64 * 32];
    int tid = threadIdx.x;
    int q0 = blockIdx.x * 64, n0 = blockIdx.y * 64, z = blockIdx.z;
    int k0 = z * KCH;
    int wave = tid >> 6, lane = tid & 63;
    int wm = wave & 1, wn = wave >> 1;
    int row16 = lane & 15, quad = lane >> 4;

    int srow = tid >> 2;
    int schunk = (tid & 3) ^ ((srow >> 1) & 3);
    const unsigned short* ga = A + (size_t)(q0 + srow) * KTOT + k0 + schunk * 8;
    const unsigned short* gb = Bm + (size_t)(n0 + srow) * KTOT + k0 + schunk * 8;
    char* lA = (char*)&As[0][0] + tid * 16;
    char* lB = (char*)&Bs[0][0] + tid * 16;

    f32x4 acc[2][2] = {};
    int fchunk = (quad ^ ((row16 >> 1) & 3)) * 8;

    gload_lds16(ga, lA);
    gload_lds16(gb, lB);
    for (int it = 0; it < NIT; ++it) {
        __syncthreads();
        if (it + 1 < NIT) {
            int nb = (it + 1) & 1;
            gload_lds16(ga + (it + 1) * 32, lA + nb * 64 * 32 * 2);
            gload_lds16(gb + (it + 1) * 32, lB + nb * 64 * 32 * 2);
        }
        int buf = it & 1;
        bf16x8 afr[2], bfr[2];
#pragma unroll
        for (int mi = 0; mi < 2; mi++)
            afr[mi] = *(const bf16x8*)&As[buf][(wm * 32 + mi * 16 + row16) * 32 + fchunk];
#pragma unroll
        for (int ni = 0; ni < 2; ni++)
            bfr[ni] = *(const bf16x8*)&Bs[buf][(wn * 32 + ni * 16 + row16) * 32 + fchunk];
#pragma unroll
        for (int mi = 0; mi < 2; mi++)
#pragma unroll
            for (int ni = 0; ni < 2; ni++)
                acc[mi][ni] = __builtin_amdgcn_mfma_f32_16x16x32_bf16(
                    afr[mi], bfr[ni], acc[mi][ni], 0, 0, 0);
    }

    float* pz = part + (size_t)z * (NQ * 512);
#pragma unroll
    for (int mi = 0; mi < 2; mi++)
#pragma unroll
        for (int ni = 0; ni < 2; ni++)
#pragma unroll
            for (int r = 0; r < 4; r++) {
                int q = q0 + wm * 32 + mi * 16 + quad * 4 + r;
                int n = n0 + wn * 32 + ni * 16 + row16;
                pz[q * 512 + n] = acc[mi][ni][r];
            }
}

// ===== L3: reduce 5 split-K partials, remap to out[b][q][r] =======================
__global__ __launch_bounds__(256) void k_reduce(const float* __restrict__ part,
                                                float* __restrict__ out) {
    int gid = blockIdx.x * 256 + threadIdx.x;   // 65536 threads
    int q = gid >> 7;
    int n = (gid & 127) * 4;
    float4 a = *(const float4*)(part + q * 512 + n);
#pragma unroll
    for (int zz = 1; zz < ZSPLIT; zz++) {
        float4 b4 = *(const float4*)(part + (size_t)zz * (NQ * 512) + q * 512 + n);
        a.x += b4.x; a.y += b4.y; a.z += b4.z; a.w += b4.w;
    }
    *(float4*)(out + (size_t)(n >> 4) * (NQ * REL_D) + q * 16 + (n & 15)) = a;
}

extern "C" void kernel_launch(void* const* d_in, const int* in_sizes, int n_in,
                              void* d_out, int out_size, void* d_ws, size_t ws_size,
                              hipStream_t stream) {
    const float* inputs  = (const float*)d_in[0];   // (32,32,32,16)
    const float* logits  = (const float*)d_in[1];   // (512,32)
    const float* filters = (const float*)d_in[2];   // (16,3,3,16)
    float* out = (float*)d_out;                     // (32,512,16)

    char* ws = (char*)d_ws;
    unsigned short* Wp = (unsigned short*)ws;                    // 1,638,400 B
    unsigned short* Bp = (unsigned short*)(ws + 1638400);        // 1,638,400 B
    float*          part = (float*)(ws + 3276800);               // 5,242,880 B

    k_front<<<NQ + BATCH, 256, 0, stream>>>(logits, inputs, filters, Wp, Bp);
    k_gemm<<<dim3(8, 8, ZSPLIT), 256, 0, stream>>>(Wp, Bp, part);
    k_reduce<<<NQ * 512 / 4 / 256, 256, 0, stream>>>(part, out);
}

// Round 8
// 107.478 us; speedup vs baseline: 1.1177x; 1.0902x over previous
//
#include <hip/hip_runtime.h>
#include <hip/hip_bf16.h>

#define N_OBJ   32
#define G_TOTAL 4960      // C(32,3) = 992 * 5 exactly
#define NPAIR   496       // C(32,2)
#define KTOT    1600      // 3*496 (pairs) + 3*32 (diag) + 16 pad
#define SEG01   0
#define SEG02   496
#define SEG12   992
#define SEGD0   1488
#define SEGD1   1520
#define SEGD2   1552
#define N_FILT  16
#define REL_D   16
#define BATCH   32
#define NQ      512
#define ZSPLIT  5
#define KCH     320       // KTOT / ZSPLIT
#define NIT     10        // KCH / 32

typedef __attribute__((ext_vector_type(8))) short bf16x8;
typedef __attribute__((ext_vector_type(4))) float f32x4;

static __device__ inline unsigned short f2bf(float x) {
    union { float f; unsigned int u; } v; v.f = x;
    unsigned int r = v.u + 0x7fffu + ((v.u >> 16) & 1u);   // RNE
    return (unsigned short)(r >> 16);
}
static __device__ inline void gload_lds16(const void* g, void* l) {
    __builtin_amdgcn_global_load_lds(
        (const __attribute__((address_space(1))) unsigned int*)g,
        (__attribute__((address_space(3))) unsigned int*)(unsigned int)(uintptr_t)l,
        16, 0, 0);
}
// base index of pairs starting with x in lexicographic C(32,2) packing:
// pbase(x) = sum_{u<x} (31-u) = x*(63-x)/2
static __device__ inline int pbase(int x) { return (x * (63 - x)) >> 1; }
// unrank lexicographic 3-combination of 32
static __device__ inline void unrank3(int g, int& a, int& b, int& c) {
    int rem = g;
    for (a = 0; a < 30; a++) { int cnt = ((31 - a) * (30 - a)) >> 1; if (rem < cnt) break; rem -= cnt; }
    for (b = a + 1; b < 31; b++) { if (rem < 31 - b) break; rem -= 31 - b; }
    c = b + 1 + rem;
}
// unrank lexicographic 2-combination of 32
static __device__ inline void unrank2(int u, int& x, int& y) {
    for (x = 0; x < 31; x++) { int len = 31 - x; if (u < len) break; u -= len; }
    y = x + 1 + u;
}
static __device__ inline float dot16(float4 a0, float4 a1, float4 a2, float4 a3,
                                     const float* F) {
    float4 f0 = *(const float4*)(F);
    float4 f1 = *(const float4*)(F + 4);
    float4 f2 = *(const float4*)(F + 8);
    float4 f3 = *(const float4*)(F + 12);
    float d = a0.x * f0.x + a0.y * f0.y + a0.z * f0.z + a0.w * f0.w;
    d += a1.x * f1.x + a1.y * f1.y + a1.z * f1.z + a1.w * f1.w;
    d += a2.x * f2.x + a2.y * f2.y + a2.z * f2.z + a2.w * f2.w;
    d += a3.x * f3.x + a3.y * f3.y + a3.z * f3.z + a3.w * f3.w;
    return d;
}

// ===== L1: packed W' rows (0..511, 1024 thr, 5 combos/thr) +
//           pairconv B' (512..639: one (batch, filter-quad) per block) ============
__global__ __launch_bounds__(1024) void k_front(const float* __restrict__ logits,
                                                const float* __restrict__ inputs,
                                                const float* __restrict__ filters,
                                                unsigned short* __restrict__ Wp,
                                                unsigned short* __restrict__ Bp) {
    __shared__ __align__(16) char smem[6656];
    int t = threadIdx.x;
    int role = blockIdx.x;

    if (role < NQ) {
        float* sp  = (float*)smem;             // 32 floats
        float* red = (float*)(smem + 128);     // 16 floats
        float* Wf  = (float*)(smem + 192);     // 1600 f32
        int q = role;
        if (t < N_OBJ) {
            float x = logits[q * N_OBJ + t];
            float ex = __expf(x);
            sp[t] = (x > 15.f) ? x : __logf(1.f + ex);
        }
        for (int i = t; i < KTOT; i += 1024) Wf[i] = 0.f;
        __syncthreads();

        // ---- single pass: product -> exp -> sum (no max-shift: args <= ~65, safe in f32)
        int g0 = t * 5;                        // 4960 = 992*5: threads 0..991 get 5 full combos
        float e[5];
        float lsum = 0.f;
        int aa, bb, cc;
        if (g0 < G_TOTAL) {
            unrank3(g0, aa, bb, cc);
            int a2 = aa, b2 = bb, c2 = cc;
#pragma unroll
            for (int k = 0; k < 5; k++) {
                e[k] = __expf(sp[a2] * sp[b2] * sp[c2]);   // BETA = 1
                lsum += e[k];
                c2++;
                if (c2 >= 32) { b2++; c2 = b2 + 1; if (c2 >= 32) { a2++; b2 = a2 + 1; c2 = b2 + 1; } }
            }
        }
#pragma unroll
        for (int off = 32; off; off >>= 1) lsum += __shfl_down(lsum, off, 64);
        if ((t & 63) == 0) red[t >> 6] = lsum;
        __syncthreads();
        float total = 0.f;
#pragma unroll
        for (int r = 0; r < 16; r++) total += red[r];
        float inv = 1.f / total;

        // ---- scatter into packed upper-tri segments (LDS atomics) ----
        if (g0 < G_TOTAL) {
            int i01 = pbase(aa) + bb - aa - 1;
            int i02 = pbase(aa) + cc - aa - 1;
            int i12 = pbase(bb) + cc - bb - 1;
            float run01 = 0.f;
#pragma unroll
            for (int k = 0; k < 5; k++) {
                float nwk = e[k] * inv;
                run01 += nwk;
                atomicAdd(&Wf[SEG02 + i02], nwk);
                atomicAdd(&Wf[SEG12 + i12], nwk);
                cc++; i02++; i12++;
                if (cc >= 32) {
                    atomicAdd(&Wf[SEG01 + i01], run01); run01 = 0.f;
                    bb++; cc = bb + 1;
                    if (cc >= 32) { aa++; bb = aa + 1; cc = bb + 1; }
                    i01 = pbase(aa) + bb - aa - 1;
                    i02 = pbase(aa) + cc - aa - 1;
                    i12 = pbase(bb) + cc - bb - 1;
                }
            }
            if (run01 != 0.f) atomicAdd(&Wf[SEG01 + i01], run01);
        }
        __syncthreads();

        // ---- diagonal marginals ----
        if (t < 96) {
            int which = t >> 5, idx = t & 31;
            float s = 0.f;
            if (which == 0) {            // Wd0[a] = sum_{b>a} W01[a,b]
                int base = pbase(idx);
                for (int u = idx + 1; u < 32; u++) s += Wf[SEG01 + base + u - idx - 1];
                Wf[SEGD0 + idx] = s;
            } else if (which == 1) {     // Wd1[b] = sum_{a<b} W01[a,b]
                for (int a2 = 0; a2 < idx; a2++) s += Wf[SEG01 + pbase(a2) + idx - a2 - 1];
                Wf[SEGD1 + idx] = s;
            } else {                     // Wd2[c] = sum_{b<c} W12[b,c]
                for (int b2 = 0; b2 < idx; b2++) s += Wf[SEG12 + pbase(b2) + idx - b2 - 1];
                Wf[SEGD2 + idx] = s;
            }
        }
        __syncthreads();

        // ---- convert + coalesced row write: 800 uints, one per thread t<800 ----
        if (t < KTOT / 2) {
            unsigned int pk = (unsigned int)f2bf(Wf[2 * t]) |
                              ((unsigned int)f2bf(Wf[2 * t + 1]) << 16);
            ((unsigned int*)(Wp + (size_t)q * KTOT))[t] = pk;
        }
    } else {
        // ---------- folded pairconv: block handles (batch b, filter quad fq) -------
        float* flt = (float*)smem;            // [4][180] floats = 2880 B
        int bid = role - NQ;                  // 0..127
        int b = bid >> 2, fq = bid & 3;
        if (t < 144) {
            int fi = t / 36, r4 = (t - fi * 36) * 4;
            *(float4*)&flt[fi * 180 + (r4 >> 4) * 20 + (r4 & 15)] =
                *(const float4*)(filters + (size_t)(fq * 4 + fi) * 144 + r4);
        }
        __syncthreads();

        if (t < 528) {
            if (t < NPAIR) {
                int x, y; unrank2(t, x, y);
                const float4* rxy = (const float4*)(inputs + (((size_t)b * 32 + x) * 32 + y) * 16);
                const float4* ryx = (const float4*)(inputs + (((size_t)b * 32 + y) * 32 + x) * 16);
                float4 a0 = rxy[0], a1 = rxy[1], a2 = rxy[2], a3 = rxy[3];
                float4 c0 = ryx[0], c1 = ryx[1], c2 = ryx[2], c3 = ryx[3];
#pragma unroll
                for (int fi = 0; fi < 4; fi++) {
                    const float* F = &flt[fi * 180];
                    float v01 = dot16(a0, a1, a2, a3, F + 1 * 20) + dot16(c0, c1, c2, c3, F + 3 * 20);
                    float v02 = dot16(a0, a1, a2, a3, F + 2 * 20) + dot16(c0, c1, c2, c3, F + 6 * 20);
                    float v12 = dot16(a0, a1, a2, a3, F + 5 * 20) + dot16(c0, c1, c2, c3, F + 7 * 20);
                    size_t nrow = ((size_t)b * 16 + fq * 4 + fi) * KTOT;
                    Bp[nrow + SEG01 + t] = f2bf(v01);
                    Bp[nrow + SEG02 + t] = f2bf(v02);
                    Bp[nrow + SEG12 + t] = f2bf(v12);
                }
            } else {
                int x = t - NPAIR;            // diagonal element
                const float4* rxx = (const float4*)(inputs + (((size_t)b * 32 + x) * 32 + x) * 16);
                float4 a0 = rxx[0], a1 = rxx[1], a2 = rxx[2], a3 = rxx[3];
#pragma unroll
                for (int fi = 0; fi < 4; fi++) {
                    const float* F = &flt[fi * 180];
                    float v0 = dot16(a0, a1, a2, a3, F + 0 * 20);
                    float v4 = dot16(a0, a1, a2, a3, F + 4 * 20);
                    float v8 = dot16(a0, a1, a2, a3, F + 8 * 20);
                    size_t nrow = ((size_t)b * 16 + fq * 4 + fi) * KTOT;
                    Bp[nrow + SEGD0 + x] = f2bf(v0);
                    Bp[nrow + SEGD1 + x] = f2bf(v4);
                    Bp[nrow + SEGD2 + x] = f2bf(v8);
                }
            }
        } else if (t < 592) {
            // zero the K-pad columns 1584..1599 for this block's 4 rows
            int idx = t - 528;
            int fi = idx >> 4, col = idx & 15;
            Bp[((size_t)b * 16 + fq * 4 + fi) * KTOT + 1584 + col] = 0;
        }
    }
}

// ===== L2: part[z] = Wp(512xK) x Bp^T tile, split-K, no atomics ===================
__global__ __launch_bounds__(256) void k_gemm(const unsigned short* __restrict__ A,
                                              const unsigned short* __restrict__ Bm,
                                              float* __restrict__ part) {
    __shared__ __align__(16) unsigned short As[2][64 * 32];
    __shared__ __align__(16) unsigned short Bs[2][64 * 32];
    int tid = threadIdx.x;
    int q0 = blockIdx.x * 64, n0 = blockIdx.y * 64, z = blockIdx.z;
    int k0 = z * KCH;
    int wave = tid >> 6, lane = tid & 63;
    int wm = wave & 1, wn = wave >> 1;
    int row16 = lane & 15, quad = lane >> 4;

    int srow = tid >> 2;
    int schunk = (tid & 3) ^ ((srow >> 1) & 3);
    const unsigned short* ga = A + (size_t)(q0 + srow) * KTOT + k0 + schunk * 8;
    const unsigned short* gb = Bm + (size_t)(n0 + srow) * KTOT + k0 + schunk * 8;
    char* lA = (char*)&As[0][0] + tid * 16;
    char* lB = (char*)&Bs[0][0] + tid * 16;

    f32x4 acc[2][2] = {};
    int fchunk = (quad ^ ((row16 >> 1) & 3)) * 8;

    gload_lds16(ga, lA);
    gload_lds16(gb, lB);
    for (int it = 0; it < NIT; ++it) {
        __syncthreads();
        if (it + 1 < NIT) {
            int nb = (it + 1) & 1;
            gload_lds16(ga + (it + 1) * 32, lA + nb * 64 * 32 * 2);
            gload_lds16(gb + (it + 1) * 32, lB + nb * 64 * 32 * 2);
        }
        int buf = it & 1;
        bf16x8 afr[2], bfr[2];
#pragma unroll
        for (int mi = 0; mi < 2; mi++)
            afr[mi] = *(const bf16x8*)&As[buf][(wm * 32 + mi * 16 + row16) * 32 + fchunk];
#pragma unroll
        for (int ni = 0; ni < 2; ni++)
            bfr[ni] = *(const bf16x8*)&Bs[buf][(wn * 32 + ni * 16 + row16) * 32 + fchunk];
#pragma unroll
        for (int mi = 0; mi < 2; mi++)
#pragma unroll
            for (int ni = 0; ni < 2; ni++)
                acc[mi][ni] = __builtin_amdgcn_mfma_f32_16x16x32_bf16(
                    afr[mi], bfr[ni], acc[mi][ni], 0, 0, 0);
    }

    float* pz = part + (size_t)z * (NQ * 512);
#pragma unroll
    for (int mi = 0; mi < 2; mi++)
#pragma unroll
        for (int ni = 0; ni < 2; ni++)
#pragma unroll
            for (int r = 0; r < 4; r++) {
                int q = q0 + wm * 32 + mi * 16 + quad * 4 + r;
                int n = n0 + wn * 32 + ni * 16 + row16;
                pz[q * 512 + n] = acc[mi][ni][r];
            }
}

// ===== L3: reduce 5 split-K partials, remap to out[b][q][r] =======================
__global__ __launch_bounds__(256) void k_reduce(const float* __restrict__ part,
                                                float* __restrict__ out) {
    int gid = blockIdx.x * 256 + threadIdx.x;   // 65536 threads
    int q = gid >> 7;
    int n = (gid & 127) * 4;
    float4 a = *(const float4*)(part + q * 512 + n);
#pragma unroll
    for (int zz = 1; zz < ZSPLIT; zz++) {
        float4 b4 = *(const float4*)(part + (size_t)zz * (NQ * 512) + q * 512 + n);
        a.x += b4.x; a.y += b4.y; a.z += b4.z; a.w += b4.w;
    }
    *(float4*)(out + (size_t)(n >> 4) * (NQ * REL_D) + q * 16 + (n & 15)) = a;
}

extern "C" void kernel_launch(void* const* d_in, const int* in_sizes, int n_in,
                              void* d_out, int out_size, void* d_ws, size_t ws_size,
                              hipStream_t stream) {
    const float* inputs  = (const float*)d_in[0];   // (32,32,32,16)
    const float* logits  = (const float*)d_in[1];   // (512,32)
    const float* filters = (const float*)d_in[2];   // (16,3,3,16)
    float* out = (float*)d_out;                     // (32,512,16)

    char* ws = (char*)d_ws;
    unsigned short* Wp = (unsigned short*)ws;                    // 1,638,400 B
    unsigned short* Bp = (unsigned short*)(ws + 1638400);        // 1,638,400 B
    float*          part = (float*)(ws + 3276800);               // 5,242,880 B

    k_front<<<NQ + 128, 1024, 0, stream>>>(logits, inputs, filters, Wp, Bp);
    k_gemm<<<dim3(8, 8, ZSPLIT), 256, 0, stream>>>(Wp, Bp, part);
    k_reduce<<<NQ * 512 / 4 / 256, 256, 0, stream>>>(part, out);
}

// Round 9
// 81.861 us; speedup vs baseline: 1.4675x; 1.3129x over previous
//
#include <hip/hip_runtime.h>
#include <hip/hip_bf16.h>

#define N_OBJ   32
#define G_TOTAL 4960      // C(32,3)
#define NPAIR   496       // C(32,2)
#define KTOT    1600      // 3*496 (pairs) + 3*32 (diag) + 16 pad
#define SEG01   0
#define SEG02   496
#define SEG12   992
#define SEGD0   1488
#define SEGD1   1520
#define SEGD2   1552
#define N_FILT  16
#define REL_D   16
#define BATCH   32
#define NQ      512
#define ZSPLIT  5
#define KCH     320       // KTOT / ZSPLIT
#define NIT     10        // KCH / 32

typedef __attribute__((ext_vector_type(8))) short bf16x8;
typedef __attribute__((ext_vector_type(4))) float f32x4;

static __device__ inline unsigned short f2bf(float x) {
    union { float f; unsigned int u; } v; v.f = x;
    unsigned int r = v.u + 0x7fffu + ((v.u >> 16) & 1u);   // RNE
    return (unsigned short)(r >> 16);
}
static __device__ inline void gload_lds16(const void* g, void* l) {
    __builtin_amdgcn_global_load_lds(
        (const __attribute__((address_space(1))) unsigned int*)g,
        (__attribute__((address_space(3))) unsigned int*)(unsigned int)(uintptr_t)l,
        16, 0, 0);
}
// base index of pairs starting with x in lexicographic C(32,2) packing
static __device__ inline int pbase(int x) { return (x * (63 - x)) >> 1; }
// unrank lexicographic 2-combination of 32
static __device__ inline void unrank2(int u, int& x, int& y) {
    for (x = 0; x < 31; x++) { int len = 31 - x; if (u < len) break; u -= len; }
    y = x + 1 + u;
}
static __device__ inline float dot16(float4 a0, float4 a1, float4 a2, float4 a3,
                                     const float* F) {
    float4 f0 = *(const float4*)(F);
    float4 f1 = *(const float4*)(F + 4);
    float4 f2 = *(const float4*)(F + 8);
    float4 f3 = *(const float4*)(F + 12);
    float d = a0.x * f0.x + a0.y * f0.y + a0.z * f0.z + a0.w * f0.w;
    d += a1.x * f1.x + a1.y * f1.y + a1.z * f1.z + a1.w * f1.w;
    d += a2.x * f2.x + a2.y * f2.y + a2.z * f2.z + a2.w * f2.w;
    d += a3.x * f3.x + a3.y * f3.y + a3.z * f3.z + a3.w * f3.w;
    return d;
}

// ===== L1a: packed W' row per block — DIRECT gather, zero atomics =================
// W01[x,y] = sum_{c>y} exp(sp x*y*c); W02[x,z] = sum_{x<b<z}; W12[y,z] = sum_{a<y}
// total = sum of W01 segment (each combo counted once at its (a,b) pair).
__global__ __launch_bounds__(1024) void k_normw(const float* __restrict__ logits,
                                                unsigned short* __restrict__ Wp) {
    __shared__ float sp[32];
    __shared__ float red[8];
    __shared__ float Wf[KTOT];
    int t = threadIdx.x;
    int q = blockIdx.x;

    if (t < N_OBJ) {
        float x = logits[q * N_OBJ + t];
        float ex = __expf(x);
        sp[t] = (x > 15.f) ? x : __logf(1.f + ex);
    }
    __syncthreads();

    // pass A: 1488 independent range-sums, no atomics
#pragma unroll
    for (int rep = 0; rep < 2; rep++) {
        int idx = t + rep * 1024;
        if (idx < 3 * NPAIR) {
            int which = idx / NPAIR;
            int u = idx - which * NPAIR;
            int x, y; unrank2(u, x, y);
            float pxy = sp[x] * sp[y];
            float s = 0.f;
            if (which == 0) {                    // W01: c in (y, 32)
                for (int c = y + 1; c < 32; c++) s += __expf(pxy * sp[c]);
            } else if (which == 1) {             // W02: b in (x, y)
                for (int c = x + 1; c < y; c++)  s += __expf(pxy * sp[c]);
            } else {                             // W12: a in [0, x)
                for (int c = 0; c < x; c++)      s += __expf(pxy * sp[c]);
            }
            Wf[which * NPAIR + u] = s;
        }
    }
    __syncthreads();

    // stage 2 (parallel roles): reduce total | diag marginals | pad zero
    if (t < 512) {
        float lsum = (t < NPAIR) ? Wf[t] : 0.f;
#pragma unroll
        for (int off = 32; off; off >>= 1) lsum += __shfl_down(lsum, off, 64);
        if ((t & 63) == 0) red[t >> 6] = lsum;
    } else if (t < 608) {
        int which = (t - 512) >> 5, idx = t & 31;
        float s = 0.f;
        if (which == 0) {                        // Wd0[a] = sum_{b>a} W01[a,b]
            int base = pbase(idx);
            for (int u = idx + 1; u < 32; u++) s += Wf[SEG01 + base + u - idx - 1];
            Wf[SEGD0 + idx] = s;
        } else if (which == 1) {                 // Wd1[b] = sum_{a<b} W01[a,b]
            for (int a2 = 0; a2 < idx; a2++) s += Wf[SEG01 + pbase(a2) + idx - a2 - 1];
            Wf[SEGD1 + idx] = s;
        } else {                                 // Wd2[c] = sum_{b<c} W12[b,c]
            for (int b2 = 0; b2 < idx; b2++) s += Wf[SEG12 + pbase(b2) + idx - b2 - 1];
            Wf[SEGD2 + idx] = s;
        }
    } else if (t < 624) {
        Wf[1584 + (t - 608)] = 0.f;              // K-pad
    }
    __syncthreads();

    // stage 3: normalize + pack + coalesced row write (800 uints)
    if (t < KTOT / 2) {
        float total = red[0] + red[1] + red[2] + red[3] +
                      red[4] + red[5] + red[6] + red[7];
        float inv = 1.f / total;
        unsigned int pk = (unsigned int)f2bf(Wf[2 * t] * inv) |
                          ((unsigned int)f2bf(Wf[2 * t + 1] * inv) << 16);
        ((unsigned int*)(Wp + (size_t)q * KTOT))[t] = pk;
    }
}

// ===== L1b: folded pairconv B' — 288 blocks (b, chunk-of-64 items) ================
__global__ __launch_bounds__(256) void k_pc(const float* __restrict__ inputs,
                                            const float* __restrict__ filters,
                                            unsigned short* __restrict__ Bp) {
    __shared__ __align__(16) float flt[16 * 180];     // all 16 filters, p-padded
    int t = threadIdx.x;
    int bid = blockIdx.x;                 // 0..287
    int b = bid / 9, ch = bid - b * 9;
    for (int i = t; i < 576; i += 256) {
        int i4 = i * 4;
        int f = i4 / 144;
        int r = i4 - f * 144;
        *(float4*)&flt[f * 180 + (r >> 4) * 20 + (r & 15)] = *(const float4*)(filters + i4);
    }
    __syncthreads();

    int lane = t & 63, fq = t >> 6;       // 4 filter-quads x 64 items
    int u = ch * 64 + lane;
    if (u < NPAIR) {
        int x, y; unrank2(u, x, y);
        const float4* rxy = (const float4*)(inputs + (((size_t)b * 32 + x) * 32 + y) * 16);
        const float4* ryx = (const float4*)(inputs + (((size_t)b * 32 + y) * 32 + x) * 16);
        float4 a0 = rxy[0], a1 = rxy[1], a2 = rxy[2], a3 = rxy[3];
        float4 c0 = ryx[0], c1 = ryx[1], c2 = ryx[2], c3 = ryx[3];
#pragma unroll
        for (int fi = 0; fi < 4; fi++) {
            const float* F = &flt[(fq * 4 + fi) * 180];
            float v01 = dot16(a0, a1, a2, a3, F + 1 * 20) + dot16(c0, c1, c2, c3, F + 3 * 20);
            float v02 = dot16(a0, a1, a2, a3, F + 2 * 20) + dot16(c0, c1, c2, c3, F + 6 * 20);
            float v12 = dot16(a0, a1, a2, a3, F + 5 * 20) + dot16(c0, c1, c2, c3, F + 7 * 20);
            size_t nrow = ((size_t)b * 16 + fq * 4 + fi) * KTOT;
            Bp[nrow + SEG01 + u] = f2bf(v01);
            Bp[nrow + SEG02 + u] = f2bf(v02);
            Bp[nrow + SEG12 + u] = f2bf(v12);
        }
    } else if (u < 528) {
        int x = u - NPAIR;                // diagonal element
        const float4* rxx = (const float4*)(inputs + (((size_t)b * 32 + x) * 32 + x) * 16);
        float4 a0 = rxx[0], a1 = rxx[1], a2 = rxx[2], a3 = rxx[3];
#pragma unroll
        for (int fi = 0; fi < 4; fi++) {
            const float* F = &flt[(fq * 4 + fi) * 180];
            float v0 = dot16(a0, a1, a2, a3, F + 0 * 20);
            float v4 = dot16(a0, a1, a2, a3, F + 4 * 20);
            float v8 = dot16(a0, a1, a2, a3, F + 8 * 20);
            size_t nrow = ((size_t)b * 16 + fq * 4 + fi) * KTOT;
            Bp[nrow + SEGD0 + x] = f2bf(v0);
            Bp[nrow + SEGD1 + x] = f2bf(v4);
            Bp[nrow + SEGD2 + x] = f2bf(v8);
        }
    } else if (ch == 8 && lane >= 16 && lane < 32) {
        int col = lane - 16;              // zero K-pad cols 1584..1599, rows fq*4..fq*4+3
#pragma unroll
        for (int fi = 0; fi < 4; fi++)
            Bp[((size_t)b * 16 + fq * 4 + fi) * KTOT + 1584 + col] = 0;
    }
}

// ===== L2: part[z] = Wp(512xK) x Bp^T tile, split-K, no atomics ===================
__global__ __launch_bounds__(256) void k_gemm(const unsigned short* __restrict__ A,
                                              const unsigned short* __restrict__ Bm,
                                              float* __restrict__ part) {
    __shared__ __align__(16) unsigned short As[2][64 * 32];
    __shared__ __align__(16) unsigned short Bs[2][64 * 32];
    int tid = threadIdx.x;
    int q0 = blockIdx.x * 64, n0 = blockIdx.y * 64, z = blockIdx.z;
    int k0 = z * KCH;
    int wave = tid >> 6, lane = tid & 63;
    int wm = wave & 1, wn = wave >> 1;
    int row16 = lane & 15, quad = lane >> 4;

    int srow = tid >> 2;
    int schunk = (tid & 3) ^ ((srow >> 1) & 3);
    const unsigned short* ga = A + (size_t)(q0 + srow) * KTOT + k0 + schunk * 8;
    const unsigned short* gb = Bm + (size_t)(n0 + srow) * KTOT + k0 + schunk * 8;
    char* lA = (char*)&As[0][0] + tid * 16;
    char* lB = (char*)&Bs[0][0] + tid * 16;

    f32x4 acc[2][2] = {};
    int fchunk = (quad ^ ((row16 >> 1) & 3)) * 8;

    gload_lds16(ga, lA);
    gload_lds16(gb, lB);
    for (int it = 0; it < NIT; ++it) {
        __syncthreads();
        if (it + 1 < NIT) {
            int nb = (it + 1) & 1;
            gload_lds16(ga + (it + 1) * 32, lA + nb * 64 * 32 * 2);
            gload_lds16(gb + (it + 1) * 32, lB + nb * 64 * 32 * 2);
        }
        int buf = it & 1;
        bf16x8 afr[2], bfr[2];
#pragma unroll
        for (int mi = 0; mi < 2; mi++)
            afr[mi] = *(const bf16x8*)&As[buf][(wm * 32 + mi * 16 + row16) * 32 + fchunk];
#pragma unroll
        for (int ni = 0; ni < 2; ni++)
            bfr[ni] = *(const bf16x8*)&Bs[buf][(wn * 32 + ni * 16 + row16) * 32 + fchunk];
#pragma unroll
        for (int mi = 0; mi < 2; mi++)
#pragma unroll
            for (int ni = 0; ni < 2; ni++)
                acc[mi][ni] = __builtin_amdgcn_mfma_f32_16x16x32_bf16(
                    afr[mi], bfr[ni], acc[mi][ni], 0, 0, 0);
    }

    float* pz = part + (size_t)z * (NQ * 512);
#pragma unroll
    for (int mi = 0; mi < 2; mi++)
#pragma unroll
        for (int ni = 0; ni < 2; ni++)
#pragma unroll
            for (int r = 0; r < 4; r++) {
                int q = q0 + wm * 32 + mi * 16 + quad * 4 + r;
                int n = n0 + wn * 32 + ni * 16 + row16;
                pz[q * 512 + n] = acc[mi][ni][r];
            }
}

// ===== L3: reduce 5 split-K partials, remap to out[b][q][r] =======================
__global__ __launch_bounds__(256) void k_reduce(const float* __restrict__ part,
                                                float* __restrict__ out) {
    int gid = blockIdx.x * 256 + threadIdx.x;   // 65536 threads
    int q = gid >> 7;
    int n = (gid & 127) * 4;
    float4 a = *(const float4*)(part + q * 512 + n);
#pragma unroll
    for (int zz = 1; zz < ZSPLIT; zz++) {
        float4 b4 = *(const float4*)(part + (size_t)zz * (NQ * 512) + q * 512 + n);
        a.x += b4.x; a.y += b4.y; a.z += b4.z; a.w += b4.w;
    }
    *(float4*)(out + (size_t)(n >> 4) * (NQ * REL_D) + q * 16 + (n & 15)) = a;
}

extern "C" void kernel_launch(void* const* d_in, const int* in_sizes, int n_in,
                              void* d_out, int out_size, void* d_ws, size_t ws_size,
                              hipStream_t stream) {
    const float* inputs  = (const float*)d_in[0];   // (32,32,32,16)
    const float* logits  = (const float*)d_in[1];   // (512,32)
    const float* filters = (const float*)d_in[2];   // (16,3,3,16)
    float* out = (float*)d_out;                     // (32,512,16)

    char* ws = (char*)d_ws;
    unsigned short* Wp = (unsigned short*)ws;                    // 1,638,400 B
    unsigned short* Bp = (unsigned short*)(ws + 1638400);        // 1,638,400 B
    float*          part = (float*)(ws + 3276800);               // 5,242,880 B

    k_normw<<<NQ, 1024, 0, stream>>>(logits, Wp);
    k_pc<<<288, 256, 0, stream>>>(inputs, filters, Bp);
    k_gemm<<<dim3(8, 8, ZSPLIT), 256, 0, stream>>>(Wp, Bp, part);
    k_reduce<<<NQ * 512 / 4 / 256, 256, 0, stream>>>(part, out);
}